// Round 2
// baseline (150.026 us; speedup 1.0000x reference)
//
#include <hip/hip_runtime.h>

// DistributionLoss: local 7x7xC std (zero-padded) of two [16,3,512,512] fp32
// tensors, smooth-L1 mean between std maps -> scalar.
//
// R9: wave-autonomous streaming design. R7/R8 post-mortem: the two-phase
// LDS structure is latency-bound (VALU 23%, HBM 22%, no pipe busy) because
// each block's global-load window is a tiny fraction of its lifetime.
//  - No LDS tiles, no interior barriers. Each 64-lane wave streams a
//    256-col x 8-row strip: 18 float4 loads/row (A,B,D quads x 3ch x 2
//    inputs), horizontal 7-tap slide in registers, vertical 7-tap via an
//    8-slot register ring (S += h_new - h_old), std + fused smooth-L1.
//  - Software pipeline: row i+2's loads issue while row i computes ->
//    ~36 loads in flight per wave; latency hidden by MLP, not occupancy.
//    1 wave/SIMD at ~350 VGPR is intentional (launch_bounds(64,1)).
//  - Unroll-by-8 inner loop keeps ring / ping-pong buffer indices
//    compile-time static (no scratch). Outer 2-iter loop NOT unrolled.
//  - OOB rows: uniform 0/1 mask multiply (exact: all ops linear in h,g).
//    OOB cols: clamp address, zero via mL/mR mask on halo channel-sums.

#define K      7
#define PAD    3
#define SH     8                 // output rows per wave strip
#define NITER  (SH + K - 1)      // 14 row-iterations
#define NT     64

__device__ __forceinline__ float4 f4z() { return make_float4(0.f, 0.f, 0.f, 0.f); }
__device__ __forceinline__ float4 add3(float4 a, float4 b, float4 c) {
    return make_float4(a.x + b.x + c.x, a.y + b.y + c.y,
                       a.z + b.z + c.z, a.w + b.w + c.w);
}
__device__ __forceinline__ float4 sq3(float4 a, float4 b, float4 c) {
    return make_float4(fmaf(a.x, a.x, fmaf(b.x, b.x, c.x * c.x)),
                       fmaf(a.y, a.y, fmaf(b.y, b.y, c.y * c.y)),
                       fmaf(a.z, a.z, fmaf(b.z, b.z, c.z * c.z)),
                       fmaf(a.w, a.w, fmaf(b.w, b.w, c.w * c.w)));
}

__global__ __launch_bounds__(NT, 1) void dist_loss_kernel(
    const float* __restrict__ pred,
    const float* __restrict__ tgt,
    float* __restrict__ out)
{
    constexpr int   C = 3, H = 512, W = 512;
    constexpr float INV_N     = 1.0f / (C * K * K);              // 1/147
    constexpr float INV_TOTAL = 1.0f / (16.0f * 512.0f * 512.0f);

    const int lane  = threadIdx.x;   // 0..63
    const int strip = blockIdx.x;    // 0..63
    const int half  = blockIdx.y;    // 0..1
    const int b     = blockIdx.z;    // 0..15

    const int ys = strip * SH;
    const int x0 = half * 256 + (lane << 2);

    const size_t plane = (size_t)H * W;
    const float* bp = pred + (size_t)b * C * plane;
    const float* bt = tgt  + (size_t)b * C * plane;

    // lane-constant column geometry
    const float mL  = (x0 > 0)   ? 1.f : 0.f;   // left halo valid
    const float mR  = (x0 < 508) ? 1.f : 0.f;   // right halo valid
    const int  offA = (x0 > 0)   ? x0 - 4 : 0;  // clamped-legal addresses;
    const int  offB = x0;                        // garbage zeroed via mL/mR
    const int  offD = (x0 < 508) ? x0 + 4 : 504;

    float4 LB[2][18];            // ping-pong load buffers (parity = iter&1)
    float4 rh[2][8], rg[2][8];   // 8-slot vertical ring per input (h, g)
    float4 S[2], Q[2];           // running 7-row sums
    float  acc = 0.f;

    #pragma unroll
    for (int w = 0; w < 2; ++w) {
        S[w] = f4z(); Q[w] = f4z();
        #pragma unroll
        for (int r = 0; r < 8; ++r) { rh[w][r] = f4z(); rg[w][r] = f4z(); }
    }

    // issue the 18 float4 loads of row-iter i_ into parity buffer P
    #define ISSUE(P, i_) do {                                              \
        const int    ly_  = ys - PAD + (i_);                               \
        const int    lyc_ = min(max(ly_, 0), H - 1);                       \
        const float* rp_  = bp + (size_t)lyc_ * W;                         \
        const float* rt_  = bt + (size_t)lyc_ * W;                         \
        LB[P][ 0] = *(const float4*)(rp_             + offA);              \
        LB[P][ 1] = *(const float4*)(rp_             + offB);              \
        LB[P][ 2] = *(const float4*)(rp_             + offD);              \
        LB[P][ 3] = *(const float4*)(rp_ +     plane + offA);              \
        LB[P][ 4] = *(const float4*)(rp_ +     plane + offB);              \
        LB[P][ 5] = *(const float4*)(rp_ +     plane + offD);              \
        LB[P][ 6] = *(const float4*)(rp_ + 2 * plane + offA);              \
        LB[P][ 7] = *(const float4*)(rp_ + 2 * plane + offB);              \
        LB[P][ 8] = *(const float4*)(rp_ + 2 * plane + offD);              \
        LB[P][ 9] = *(const float4*)(rt_             + offA);              \
        LB[P][10] = *(const float4*)(rt_             + offB);              \
        LB[P][11] = *(const float4*)(rt_             + offD);              \
        LB[P][12] = *(const float4*)(rt_ +     plane + offA);              \
        LB[P][13] = *(const float4*)(rt_ +     plane + offB);              \
        LB[P][14] = *(const float4*)(rt_ +     plane + offD);              \
        LB[P][15] = *(const float4*)(rt_ + 2 * plane + offA);              \
        LB[P][16] = *(const float4*)(rt_ + 2 * plane + offB);              \
        LB[P][17] = *(const float4*)(rt_ + 2 * plane + offD);              \
    } while (0)

    ISSUE(0, 0);
    ISSUE(1, 1);

    #pragma unroll 1
    for (int g = 0; g < 2; ++g) {
        #pragma unroll
        for (int j = 0; j < 8; ++j) {
            const int i = g * 8 + j;        // uniform (scalar) iteration id
            if (i < NITER) {
                const int   ly = ys - PAD + i;
                const float m  = ((unsigned)ly < (unsigned)H) ? 1.f : 0.f;

                #pragma unroll
                for (int w = 0; w < 2; ++w) {
                    float4 A0 = LB[j & 1][w * 9 + 0];
                    float4 B0 = LB[j & 1][w * 9 + 1];
                    float4 D0 = LB[j & 1][w * 9 + 2];
                    float4 A1 = LB[j & 1][w * 9 + 3];
                    float4 B1 = LB[j & 1][w * 9 + 4];
                    float4 D1 = LB[j & 1][w * 9 + 5];
                    float4 A2 = LB[j & 1][w * 9 + 6];
                    float4 B2 = LB[j & 1][w * 9 + 7];
                    float4 D2 = LB[j & 1][w * 9 + 8];

                    float4 tl = add3(A0, A1, A2);
                    float4 ta = add3(B0, B1, B2);
                    float4 tb = add3(D0, D1, D2);
                    float4 ul = sq3(A0, A1, A2);
                    float4 ua = sq3(B0, B1, B2);
                    float4 ub = sq3(D0, D1, D2);

                    // zero the (clamped-address) halo columns at image edges
                    tl.y *= mL; tl.z *= mL; tl.w *= mL;
                    ul.y *= mL; ul.z *= mL; ul.w *= mL;
                    tb.x *= mR; tb.y *= mR; tb.z *= mR;
                    ub.x *= mR; ub.y *= mR; ub.z *= mR;

                    // horizontal 7-tap sliding window
                    float h0 = tl.y + tl.z + tl.w + ta.x + ta.y + ta.z + ta.w;
                    float h1 = h0 - tl.y + tb.x;
                    float h2 = h1 - tl.z + tb.y;
                    float h3 = h2 - tl.w + tb.z;
                    float g0 = ul.y + ul.z + ul.w + ua.x + ua.y + ua.z + ua.w;
                    float g1 = g0 - ul.y + ub.x;
                    float g2 = g1 - ul.z + ub.y;
                    float g3 = g2 - ul.w + ub.z;

                    float4 hm = make_float4(h0 * m, h1 * m, h2 * m, h3 * m);
                    float4 gm = make_float4(g0 * m, g1 * m, g2 * m, g3 * m);

                    // vertical ring update: S covers rows i-6..i after this
                    float4 ho = rh[w][(j + 1) & 7];
                    float4 go = rg[w][(j + 1) & 7];
                    S[w].x += hm.x - ho.x; S[w].y += hm.y - ho.y;
                    S[w].z += hm.z - ho.z; S[w].w += hm.w - ho.w;
                    Q[w].x += gm.x - go.x; Q[w].y += gm.y - go.y;
                    Q[w].z += gm.z - go.z; Q[w].w += gm.w - go.w;
                    rh[w][j] = hm; rg[w][j] = gm;
                }

                if (i >= K - 1) {   // ring primed: output row ys + i - 6
                    float4 sd[2];
                    #pragma unroll
                    for (int w = 0; w < 2; ++w) {
                        float mux = S[w].x * INV_N, muy = S[w].y * INV_N,
                              muz = S[w].z * INV_N, muw = S[w].w * INV_N;
                        sd[w].x = sqrtf(fmaf(-mux, mux, Q[w].x * INV_N) + 1e-8f);
                        sd[w].y = sqrtf(fmaf(-muy, muy, Q[w].y * INV_N) + 1e-8f);
                        sd[w].z = sqrtf(fmaf(-muz, muz, Q[w].z * INV_N) + 1e-8f);
                        sd[w].w = sqrtf(fmaf(-muw, muw, Q[w].w * INV_N) + 1e-8f);
                    }
                    #define SL1(a, bb)                                         \
                        {                                                      \
                            float d  = (a) - (bb);                             \
                            float ad = fabsf(d);                               \
                            acc += (ad < 1.0f) ? 0.5f * d * d : (ad - 0.5f);   \
                        }
                    SL1(sd[0].x, sd[1].x); SL1(sd[0].y, sd[1].y);
                    SL1(sd[0].z, sd[1].z); SL1(sd[0].w, sd[1].w);
                    #undef SL1
                }

                if (i + 2 < NITER) { ISSUE(j & 1, i + 2); }
            }
        }
    }
    #undef ISSUE

    // wave reduction + one atomic per wave
    #pragma unroll
    for (int off = 32; off > 0; off >>= 1)
        acc += __shfl_down(acc, off, 64);
    if (lane == 0) atomicAdd(out, acc * INV_TOTAL);
}

extern "C" void kernel_launch(void* const* d_in, const int* in_sizes, int n_in,
                              void* d_out, int out_size, void* d_ws, size_t ws_size,
                              hipStream_t stream) {
    const float* pred = (const float*)d_in[0];
    const float* tgt  = (const float*)d_in[1];
    float* out = (float*)d_out;

    hipMemsetAsync(out, 0, sizeof(float), stream);

    dim3 grid(512 / SH, 2, 16);   // 64 strips x 2 halves x 16 batches = 2048 waves
    dist_loss_kernel<<<grid, NT, 0, stream>>>(pred, tgt, out);
}

// Round 3
// 130.192 us; speedup vs baseline: 1.1523x; 1.1523x over previous
//
#include <hip/hip_runtime.h>

// DistributionLoss: local 7x7xC std (zero-padded) of two [16,3,512,512] fp32
// tensors, smooth-L1 mean between std maps -> scalar.
//
// R11: R8's two-phase LDS structure + PINNED load pipeline.
// R8/R9 post-mortem: hipcc JITs global loads to minimize VGPR pressure
// (R8: VGPR=52, R9: 196 vs ~310 needed), serializing ~900cy HBM latencies
// -> ~2KB/CU in flight vs 9.2KB needed -> stuck at 1.3-1.8 TB/s.
// Fix (T14/HK reg-staging): inline-asm global_load_dwordx4 (issue order
// pinned by asm-volatile) + counted s_waitcnt vmcnt(N) + sched_barrier(0).
// Phase A = 3 unrolled task stages/thread, 24 quads (24.6KB/wave) in
// flight. Halo loads use clamped addresses + 0/1 mask multiply (always
// legal, no divergence -> wave-uniform vmcnt counts; no other VMEM between
// issue and wait). launch_bounds(256,2): VGPR cap 256, ~2 blocks/CU --
// latency hidden by MLP, not TLP. Phase B + reduction = R8 verbatim.

typedef float f32x4 __attribute__((ext_vector_type(4)));

#define K     7
#define PAD   3
#define TSX   64
#define TSY   32
#define HR    (TSY + K - 1)   // 38 halo rows
#define LDSW  64              // LDS row stride (floats)
#define NT    256
#define NTASK (2 * HR * 8)    // 608 fused tasks (both inputs)

#define LOADQ(dst, ptr, OFF)                                        \
    asm volatile("global_load_dwordx4 %0, %1, off offset:" OFF      \
                 : "=v"(dst) : "v"(ptr))

#define WAITV(N) do {                                               \
    asm volatile("s_waitcnt vmcnt(" #N ")" ::: "memory");           \
    __builtin_amdgcn_sched_barrier(0);                              \
} while (0)

__global__ __launch_bounds__(NT, 2) void dist_loss_kernel(
    const float* __restrict__ pred,
    const float* __restrict__ tgt,
    float* __restrict__ out)
{
    constexpr int   C = 3, H = 512, W = 512;
    constexpr float INV_N     = 1.0f / (C * K * K);              // 1/147
    constexpr float INV_TOTAL = 1.0f / (16.0f * 512.0f * 512.0f);

    __shared__ float sh_s[2][HR][LDSW];   // horizontal 7-tap of channel sum
    __shared__ float sh_q[2][HR][LDSW];   // horizontal 7-tap of channel sum-sq

    const int    tid  = threadIdx.x;
    const int    tx0  = blockIdx.x * TSX;
    const int    ty0  = blockIdx.y * TSY;
    const int    b    = blockIdx.z;
    const size_t plane = (size_t)H * W;

    const float* base0 = pred + (size_t)b * C * plane;
    const float* base1 = tgt  + (size_t)b * C * plane;

    float* shs = &sh_s[0][0][0];
    float* shq = &sh_q[0][0][0];

    // ---- Phase A: 3-deep pinned pipeline, 12 asm loads per task ----
    #define DECL_SLOT(S)                                                     \
        const float *rB0_##S, *rB1_##S, *rB2_##S,                            \
                    *pA0_##S, *pA1_##S, *pA2_##S,                            \
                    *pE0_##S, *pE1_##S, *pE2_##S;                            \
        f32x4 qA0_##S, qB0_##S, qD0_##S, qE0_##S,                            \
              qA1_##S, qB1_##S, qD1_##S, qE1_##S,                            \
              qA2_##S, qB2_##S, qD2_##S, qE2_##S;                            \
        float m_##S, mL_##S, mR_##S; int idx_##S;

    // decode task t; clamped (always-legal) addresses; garbage masked later
    #define SETUP(S, t) do {                                                 \
        const int which = ((t) >= HR * 8) ? 1 : 0;                           \
        const int tt    = (t) - which * (HR * 8);                            \
        const int row   = tt >> 3, cg = tt & 7;                              \
        const int gy    = ty0 - PAD + row;                                   \
        m_##S  = ((unsigned)gy < (unsigned)H) ? 1.f : 0.f;                   \
        const int gyc = min(max(gy, 0), H - 1);                              \
        const int gx0 = tx0 + (cg << 3);                                     \
        mL_##S = (gx0 > 0)   ? 1.f : 0.f;                                    \
        mR_##S = (gx0 < 504) ? 1.f : 0.f;                                    \
        const float* base = which ? base1 : base0;                           \
        rB0_##S = base + (size_t)gyc * W + gx0;                              \
        rB1_##S = rB0_##S + plane;                                           \
        rB2_##S = rB1_##S + plane;                                           \
        pA0_##S = rB0_##S + ((gx0 > 0)   ? -4 : 0);                          \
        pA1_##S = pA0_##S + plane;                                           \
        pA2_##S = pA1_##S + plane;                                           \
        pE0_##S = rB0_##S + ((gx0 < 504) ?  4 : 0);  /* +offset:16 => E */   \
        pE1_##S = pE0_##S + plane;                                           \
        pE2_##S = pE1_##S + plane;                                           \
        idx_##S = (which * HR + row) * LDSW + (cg << 3);                     \
    } while (0)

    #define ISSUE(S) do {                                                    \
        LOADQ(qA0_##S, pA0_##S, "0");  LOADQ(qB0_##S, rB0_##S, "0");         \
        LOADQ(qD0_##S, rB0_##S, "16"); LOADQ(qE0_##S, pE0_##S, "16");        \
        LOADQ(qA1_##S, pA1_##S, "0");  LOADQ(qB1_##S, rB1_##S, "0");         \
        LOADQ(qD1_##S, rB1_##S, "16"); LOADQ(qE1_##S, pE1_##S, "16");        \
        LOADQ(qA2_##S, pA2_##S, "0");  LOADQ(qB2_##S, rB2_##S, "0");         \
        LOADQ(qD2_##S, rB2_##S, "16"); LOADQ(qE2_##S, pE2_##S, "16");        \
    } while (0)

    #define CONSUME(S) do {                                                  \
        f32x4 tl = qA0_##S + qA1_##S + qA2_##S;                              \
        f32x4 ta = qB0_##S + qB1_##S + qB2_##S;                              \
        f32x4 tb = qD0_##S + qD1_##S + qD2_##S;                              \
        f32x4 tr = qE0_##S + qE1_##S + qE2_##S;                              \
        f32x4 ul = qA0_##S*qA0_##S + qA1_##S*qA1_##S + qA2_##S*qA2_##S;      \
        f32x4 ua = qB0_##S*qB0_##S + qB1_##S*qB1_##S + qB2_##S*qB2_##S;      \
        f32x4 ub = qD0_##S*qD0_##S + qD1_##S*qD1_##S + qD2_##S*qD2_##S;      \
        f32x4 ur = qE0_##S*qE0_##S + qE1_##S*qE1_##S + qE2_##S*qE2_##S;      \
        tl[1] *= mL_##S; tl[2] *= mL_##S; tl[3] *= mL_##S;                   \
        ul[1] *= mL_##S; ul[2] *= mL_##S; ul[3] *= mL_##S;                   \
        tr[0] *= mR_##S; tr[1] *= mR_##S; tr[2] *= mR_##S;                   \
        ur[0] *= mR_##S; ur[1] *= mR_##S; ur[2] *= mR_##S;                   \
        float h0 = tl[1]+tl[2]+tl[3]+ta[0]+ta[1]+ta[2]+ta[3];                \
        float h1 = h0 - tl[1] + tb[0];                                       \
        float h2 = h1 - tl[2] + tb[1];                                       \
        float h3 = h2 - tl[3] + tb[2];                                       \
        float h4 = h3 - ta[0] + tb[3];                                       \
        float h5 = h4 - ta[1] + tr[0];                                       \
        float h6 = h5 - ta[2] + tr[1];                                       \
        float h7 = h6 - ta[3] + tr[2];                                       \
        float g0 = ul[1]+ul[2]+ul[3]+ua[0]+ua[1]+ua[2]+ua[3];                \
        float g1 = g0 - ul[1] + ub[0];                                       \
        float g2 = g1 - ul[2] + ub[1];                                       \
        float g3 = g2 - ul[3] + ub[2];                                       \
        float g4 = g3 - ua[0] + ub[3];                                       \
        float g5 = g4 - ua[1] + ur[0];                                       \
        float g6 = g5 - ua[2] + ur[1];                                       \
        float g7 = g6 - ua[3] + ur[2];                                       \
        const float mm = m_##S;                                              \
        *(f32x4*)&shs[idx_##S]     = (f32x4){h0*mm, h1*mm, h2*mm, h3*mm};    \
        *(f32x4*)&shs[idx_##S + 4] = (f32x4){h4*mm, h5*mm, h6*mm, h7*mm};    \
        *(f32x4*)&shq[idx_##S]     = (f32x4){g0*mm, g1*mm, g2*mm, g3*mm};    \
        *(f32x4*)&shq[idx_##S + 4] = (f32x4){g4*mm, g5*mm, g6*mm, g7*mm};    \
    } while (0)

    DECL_SLOT(0);
    DECL_SLOT(1);
    const int t0 = tid;
    const int t1 = tid + NT;
    const int t2 = min(tid + 2 * NT, NTASK - 1);  // dup tail: benign same-value writes

    SETUP(0, t0); ISSUE(0);
    SETUP(1, t1); ISSUE(1);
    WAITV(12);            // T0's 12 loads done; T1's 12 still in flight
    CONSUME(0);
    SETUP(0, t2); ISSUE(0);
    WAITV(12);            // T1 done; T2 in flight
    CONSUME(1);
    WAITV(0);             // T2 done
    CONSUME(0);

    __syncthreads();

    // ---- Phase B: vertical 7-tap + std + fused smooth-L1; 2 rows/thread
    float acc = 0.0f;
    {
        const int rp = tid >> 4;          // row pair 0..15
        const int x  = (tid & 15) << 2;   // col within tile

        f32x4 pA, pB;                     // input 0 std quads

        #define STD4(Sv, Qv, D) do {                                         \
            _Pragma("unroll")                                                \
            for (int c_ = 0; c_ < 4; ++c_) {                                 \
                float mu_ = (Sv)[c_] * INV_N;                                \
                (D)[c_] = sqrtf(fmaf(-mu_, mu_, (Qv)[c_] * INV_N) + 1e-8f);  \
            }                                                                \
        } while (0)
        #define SL1(a, bb) do {                                              \
            float d_  = (a) - (bb);                                          \
            float ad_ = fabsf(d_);                                           \
            acc += (ad_ < 1.0f) ? 0.5f * d_ * d_ : (ad_ - 0.5f);             \
        } while (0)

        #pragma unroll
        for (int w = 0; w < 2; ++w) {
            f32x4 S = (f32x4){0.f, 0.f, 0.f, 0.f};
            f32x4 Q = (f32x4){0.f, 0.f, 0.f, 0.f};
            #pragma unroll
            for (int k = 0; k < K; ++k) {
                S += *(const f32x4*)&sh_s[w][2 * rp + k][x];
                Q += *(const f32x4*)&sh_q[w][2 * rp + k][x];
            }
            f32x4 S2 = S - *(const f32x4*)&sh_s[w][2 * rp][x]
                         + *(const f32x4*)&sh_s[w][2 * rp + 7][x];
            f32x4 Q2 = Q - *(const f32x4*)&sh_q[w][2 * rp][x]
                         + *(const f32x4*)&sh_q[w][2 * rp + 7][x];

            if (w == 0) {
                STD4(S, Q, pA);
                STD4(S2, Q2, pB);
            } else {
                f32x4 sA, sB;
                STD4(S, Q, sA);
                STD4(S2, Q2, sB);
                SL1(pA[0], sA[0]); SL1(pA[1], sA[1]);
                SL1(pA[2], sA[2]); SL1(pA[3], sA[3]);
                SL1(pB[0], sB[0]); SL1(pB[1], sB[1]);
                SL1(pB[2], sB[2]); SL1(pB[3], sB[3]);
            }
        }
        #undef STD4
        #undef SL1
    }

    // ---- block reduction: wave64 shuffle, cross-wave via LDS, one atomic
    #pragma unroll
    for (int off = 32; off > 0; off >>= 1)
        acc += __shfl_down(acc, off, 64);

    __shared__ float wave_sums[NT / 64];
    if ((tid & 63) == 0) wave_sums[tid >> 6] = acc;
    __syncthreads();
    if (tid == 0) {
        float s = 0.0f;
        #pragma unroll
        for (int w = 0; w < NT / 64; ++w) s += wave_sums[w];
        atomicAdd(out, s * INV_TOTAL);
    }
}

extern "C" void kernel_launch(void* const* d_in, const int* in_sizes, int n_in,
                              void* d_out, int out_size, void* d_ws, size_t ws_size,
                              hipStream_t stream) {
    const float* pred = (const float*)d_in[0];
    const float* tgt  = (const float*)d_in[1];
    float* out = (float*)d_out;

    hipMemsetAsync(out, 0, sizeof(float), stream);

    dim3 grid(512 / TSX, 512 / TSY, 16);   // 8 x 16 x 16 = 2048 blocks
    dist_loss_kernel<<<grid, NT, 0, stream>>>(pred, tgt, out);
}

// Round 4
// 128.457 us; speedup vs baseline: 1.1679x; 1.0135x over previous
//
#include <hip/hip_runtime.h>

// DistributionLoss: local 7x7xC std (zero-padded) of two [16,3,512,512] fp32
// tensors, smooth-L1 mean between std maps -> scalar.
//
// R12: cross-tile pinned pipeline. R11 post-mortem: pinned loads fixed issue
// ORDER (2.32 TB/s) but memory duty cycle is ~10%: each block bursts 36
// loads at start, then the pipe idles through Phase B + barrier + reduce.
// Fix: one block owns NTILE=4 vertically-adjacent tiles; the 3-slot pinned
// pipeline ROLLS across tiles (consume slot -> immediately re-issue slot
// with next tile's task), so 24-36 quads stay in flight across Phase B and
// the barrier. Uniform s_waitcnt vmcnt(24) in steady state; epilogue drains
// 24/12/0. Double-buffered LDS (76 KB, 2 blocks/CU) -> ONE barrier/tile.
// Grid 8x4x16 = 512 blocks = exactly 2/CU, no tail. Reduction paid once
// per 4 tiles. launch_bounds(256,2) -> VGPR cap 256 (2 waves/SIMD), holds
// 36 asm-output quads (144 VGPR) live across Phase B by design.

typedef float f32x4 __attribute__((ext_vector_type(4)));

#define K     7
#define PAD   3
#define TSX   64
#define TSY   32
#define HR    (TSY + K - 1)   // 38 halo rows
#define LDSW  64              // LDS row stride (floats)
#define NT    256
#define NTASK (2 * HR * 8)    // 608 tasks per tile (both inputs)
#define NTILE 4               // vertical tiles per block

#define LOADQ(dst, ptr, OFF)                                        \
    asm volatile("global_load_dwordx4 %0, %1, off offset:" OFF      \
                 : "=v"(dst) : "v"(ptr))

#define WAITV(N) do {                                               \
    asm volatile("s_waitcnt vmcnt(" #N ")" ::: "memory");           \
    __builtin_amdgcn_sched_barrier(0);                              \
} while (0)

__global__ __launch_bounds__(NT, 2) void dist_loss_kernel(
    const float* __restrict__ pred,
    const float* __restrict__ tgt,
    float* __restrict__ out)
{
    constexpr int   C = 3, H = 512, W = 512;
    constexpr float INV_N     = 1.0f / (C * K * K);              // 1/147
    constexpr float INV_TOTAL = 1.0f / (16.0f * 512.0f * 512.0f);

    extern __shared__ float smem[];
    float* shs = smem;                       // [2 buf][2 which][HR][LDSW]
    float* shq = smem + 2 * 2 * HR * LDSW;   // same shape
    float* wave_sums = shq + 2 * 2 * HR * LDSW;   // [NT/64]

    const int    tid  = threadIdx.x;
    const int    tx0  = blockIdx.x * TSX;
    const int    tyb  = blockIdx.y * (NTILE * TSY);   // block's first tile row
    const int    b    = blockIdx.z;
    const size_t plane = (size_t)H * W;

    const float* base0 = pred + (size_t)b * C * plane;
    const float* base1 = tgt  + (size_t)b * C * plane;

    const int rp = tid >> 4;          // Phase B: row pair 0..15
    const int x  = (tid & 15) << 2;   // Phase B: col within tile

    // ---- slot state: 12 asm-output quads + masks + LDS index ----
    #define DECL_SLOT(S)                                                     \
        f32x4 qA0_##S, qB0_##S, qD0_##S, qE0_##S,                            \
              qA1_##S, qB1_##S, qD1_##S, qE1_##S,                            \
              qA2_##S, qB2_##S, qD2_##S, qE2_##S;                            \
        float m_##S, mL_##S, mR_##S; int idx_##S;

    // setup + issue: decode task t for tile at TY0, write into buffer BUF.
    // Clamped (always-legal) addresses; halo garbage masked in CONSUME.
    #define SI(S, t, TY0, BUF) do {                                          \
        const int which = ((t) >= HR * 8) ? 1 : 0;                           \
        const int tt    = (t) - which * (HR * 8);                            \
        const int row   = tt >> 3, cg = tt & 7;                              \
        const int gy    = (TY0) - PAD + row;                                 \
        m_##S  = ((unsigned)gy < (unsigned)H) ? 1.f : 0.f;                   \
        const int gyc = min(max(gy, 0), H - 1);                              \
        const int gx0 = tx0 + (cg << 3);                                     \
        mL_##S = (gx0 > 0)   ? 1.f : 0.f;                                    \
        mR_##S = (gx0 < 504) ? 1.f : 0.f;                                    \
        const float* base = which ? base1 : base0;                           \
        const float* rB0 = base + (size_t)gyc * W + gx0;                     \
        const float* rB1 = rB0 + plane;                                      \
        const float* rB2 = rB1 + plane;                                      \
        const float* pA0 = rB0 + ((gx0 > 0)   ? -4 : 0);                     \
        const float* pA1 = pA0 + plane;                                      \
        const float* pA2 = pA1 + plane;                                      \
        const float* pE0 = rB0 + ((gx0 < 504) ?  4 : 0);  /* +16 => E */     \
        const float* pE1 = pE0 + plane;                                      \
        const float* pE2 = pE1 + plane;                                      \
        idx_##S = (((BUF) * 2 + which) * HR + row) * LDSW + (cg << 3);       \
        LOADQ(qA0_##S, pA0, "0");  LOADQ(qB0_##S, rB0, "0");                 \
        LOADQ(qD0_##S, rB0, "16"); LOADQ(qE0_##S, pE0, "16");                \
        LOADQ(qA1_##S, pA1, "0");  LOADQ(qB1_##S, rB1, "0");                 \
        LOADQ(qD1_##S, rB1, "16"); LOADQ(qE1_##S, pE1, "16");                \
        LOADQ(qA2_##S, pA2, "0");  LOADQ(qB2_##S, rB2, "0");                 \
        LOADQ(qD2_##S, rB2, "16"); LOADQ(qE2_##S, pE2, "16");                \
    } while (0)

    #define CONSUME(S) do {                                                  \
        f32x4 tl = qA0_##S + qA1_##S + qA2_##S;                              \
        f32x4 ta = qB0_##S + qB1_##S + qB2_##S;                              \
        f32x4 tb = qD0_##S + qD1_##S + qD2_##S;                              \
        f32x4 tr = qE0_##S + qE1_##S + qE2_##S;                              \
        f32x4 ul = qA0_##S*qA0_##S + qA1_##S*qA1_##S + qA2_##S*qA2_##S;      \
        f32x4 ua = qB0_##S*qB0_##S + qB1_##S*qB1_##S + qB2_##S*qB2_##S;      \
        f32x4 ub = qD0_##S*qD0_##S + qD1_##S*qD1_##S + qD2_##S*qD2_##S;      \
        f32x4 ur = qE0_##S*qE0_##S + qE1_##S*qE1_##S + qE2_##S*qE2_##S;      \
        tl[1] *= mL_##S; tl[2] *= mL_##S; tl[3] *= mL_##S;                   \
        ul[1] *= mL_##S; ul[2] *= mL_##S; ul[3] *= mL_##S;                   \
        tr[0] *= mR_##S; tr[1] *= mR_##S; tr[2] *= mR_##S;                   \
        ur[0] *= mR_##S; ur[1] *= mR_##S; ur[2] *= mR_##S;                   \
        float h0 = tl[1]+tl[2]+tl[3]+ta[0]+ta[1]+ta[2]+ta[3];                \
        float h1 = h0 - tl[1] + tb[0];                                       \
        float h2 = h1 - tl[2] + tb[1];                                       \
        float h3 = h2 - tl[3] + tb[2];                                       \
        float h4 = h3 - ta[0] + tb[3];                                       \
        float h5 = h4 - ta[1] + tr[0];                                       \
        float h6 = h5 - ta[2] + tr[1];                                       \
        float h7 = h6 - ta[3] + tr[2];                                       \
        float g0 = ul[1]+ul[2]+ul[3]+ua[0]+ua[1]+ua[2]+ua[3];                \
        float g1 = g0 - ul[1] + ub[0];                                       \
        float g2 = g1 - ul[2] + ub[1];                                       \
        float g3 = g2 - ul[3] + ub[2];                                       \
        float g4 = g3 - ua[0] + ub[3];                                       \
        float g5 = g4 - ua[1] + ur[0];                                       \
        float g6 = g5 - ua[2] + ur[1];                                       \
        float g7 = g6 - ua[3] + ur[2];                                       \
        const float mm = m_##S;                                              \
        *(f32x4*)&shs[idx_##S]     = (f32x4){h0*mm, h1*mm, h2*mm, h3*mm};    \
        *(f32x4*)&shs[idx_##S + 4] = (f32x4){h4*mm, h5*mm, h6*mm, h7*mm};    \
        *(f32x4*)&shq[idx_##S]     = (f32x4){g0*mm, g1*mm, g2*mm, g3*mm};    \
        *(f32x4*)&shq[idx_##S + 4] = (f32x4){g4*mm, g5*mm, g6*mm, g7*mm};    \
    } while (0)

    #define STD4(Sv, Qv, D) do {                                             \
        _Pragma("unroll")                                                    \
        for (int c_ = 0; c_ < 4; ++c_) {                                     \
            float mu_ = (Sv)[c_] * INV_N;                                    \
            (D)[c_] = sqrtf(fmaf(-mu_, mu_, (Qv)[c_] * INV_N) + 1e-8f);      \
        }                                                                    \
    } while (0)
    #define SL1(a, bb) do {                                                  \
        float d_  = (a) - (bb);                                              \
        float ad_ = fabsf(d_);                                               \
        acc += (ad_ < 1.0f) ? 0.5f * d_ * d_ : (ad_ - 0.5f);                 \
    } while (0)

    // Phase B on buffer BF: vertical 7-tap + std + fused smooth-L1
    #define PHASE_B(BF) do {                                                 \
        const float* bs_ = shs + (BF) * (2 * HR * LDSW);                     \
        const float* bq_ = shq + (BF) * (2 * HR * LDSW);                     \
        f32x4 pA, pB;                                                        \
        _Pragma("unroll")                                                    \
        for (int w = 0; w < 2; ++w) {                                        \
            const float* rs_ = bs_ + w * (HR * LDSW);                        \
            const float* rq_ = bq_ + w * (HR * LDSW);                        \
            f32x4 S = (f32x4){0.f, 0.f, 0.f, 0.f};                           \
            f32x4 Q = (f32x4){0.f, 0.f, 0.f, 0.f};                           \
            _Pragma("unroll")                                                \
            for (int k = 0; k < K; ++k) {                                    \
                S += *(const f32x4*)&rs_[(2 * rp + k) * LDSW + x];           \
                Q += *(const f32x4*)&rq_[(2 * rp + k) * LDSW + x];           \
            }                                                                \
            f32x4 S2 = S - *(const f32x4*)&rs_[(2 * rp) * LDSW + x]          \
                         + *(const f32x4*)&rs_[(2 * rp + 7) * LDSW + x];     \
            f32x4 Q2 = Q - *(const f32x4*)&rq_[(2 * rp) * LDSW + x]          \
                         + *(const f32x4*)&rq_[(2 * rp + 7) * LDSW + x];     \
            if (w == 0) {                                                    \
                STD4(S, Q, pA);                                              \
                STD4(S2, Q2, pB);                                            \
            } else {                                                         \
                f32x4 sA, sB;                                                \
                STD4(S, Q, sA);                                              \
                STD4(S2, Q2, sB);                                            \
                SL1(pA[0], sA[0]); SL1(pA[1], sA[1]);                        \
                SL1(pA[2], sA[2]); SL1(pA[3], sA[3]);                        \
                SL1(pB[0], sB[0]); SL1(pB[1], sB[1]);                        \
                SL1(pB[2], sB[2]); SL1(pB[3], sB[3]);                        \
            }                                                                \
        }                                                                    \
    } while (0)

    DECL_SLOT(0);
    DECL_SLOT(1);
    DECL_SLOT(2);
    const int t0 = tid;
    const int t1 = tid + NT;
    const int t2 = min(tid + 2 * NT, NTASK - 1);  // dup tail: benign same-value writes

    float acc = 0.0f;

    // prologue: tile 0's 36 loads in flight
    SI(0, t0, tyb, 0);
    SI(1, t1, tyb, 0);
    SI(2, t2, tyb, 0);

    // steady state: consume slot -> immediately re-issue with next tile's task.
    // vmcnt: 36 outstanding at each WAITV(24); oldest 12 = the consumed slot.
    #pragma unroll
    for (int n = 0; n < NTILE - 1; ++n) {
        const int tyn = tyb + (n + 1) * TSY;
        const int pn  = (n + 1) & 1;
        WAITV(24); CONSUME(0); SI(0, t0, tyn, pn);
        WAITV(24); CONSUME(1); SI(1, t1, tyn, pn);
        WAITV(24); CONSUME(2); SI(2, t2, tyn, pn);
        __syncthreads();
        PHASE_B(n & 1);
        // no 2nd barrier: next consumes write buf[(n+1)&1] != buf[n&1];
        // the overwrite of buf[n&1] happens only after iter n+1's barrier.
    }

    // epilogue: last tile, drain 24/12/0
    WAITV(24); CONSUME(0);
    WAITV(12); CONSUME(1);
    WAITV(0);  CONSUME(2);
    __syncthreads();
    PHASE_B((NTILE - 1) & 1);

    #undef SI
    #undef CONSUME
    #undef PHASE_B
    #undef STD4
    #undef SL1

    // ---- block reduction: wave64 shuffle, cross-wave via LDS, one atomic
    #pragma unroll
    for (int off = 32; off > 0; off >>= 1)
        acc += __shfl_down(acc, off, 64);

    __syncthreads();   // buffers dead; reuse LDS tail for wave sums
    if ((tid & 63) == 0) wave_sums[tid >> 6] = acc;
    __syncthreads();
    if (tid == 0) {
        float s = 0.0f;
        #pragma unroll
        for (int w = 0; w < NT / 64; ++w) s += wave_sums[w];
        atomicAdd(out, s * INV_TOTAL);
    }
}

extern "C" void kernel_launch(void* const* d_in, const int* in_sizes, int n_in,
                              void* d_out, int out_size, void* d_ws, size_t ws_size,
                              hipStream_t stream) {
    const float* pred = (const float*)d_in[0];
    const float* tgt  = (const float*)d_in[1];
    float* out = (float*)d_out;

    hipMemsetAsync(out, 0, sizeof(float), stream);

    // dynamic LDS: 2 bufs x 2 which x HR x LDSW floats x 2 arrays + 4 wave sums
    const size_t lds_bytes = (2 * 2 * HR * LDSW * 2 + 4) * sizeof(float);

    dim3 grid(512 / TSX, 512 / (TSY * NTILE), 16);   // 8 x 4 x 16 = 512 blocks
    dist_loss_kernel<<<grid, NT, lds_bytes, stream>>>(pred, tgt, out);
}

// Round 6
// 123.697 us; speedup vs baseline: 1.2129x; 1.0385x over previous
//
#include <hip/hip_runtime.h>

// DistributionLoss: local 7x7xC std (zero-padded) of two [16,3,512,512] fp32
// tensors, smooth-L1 mean between std maps -> scalar.
//
// R14 == R13 resubmitted after an infra container failure (no counters came
// back; audit found no hang/fault path: vmcnt ledger exact and always
// satisfiable, barriers wave-uniform, all addresses clamped in-bounds,
// ring/slot algebra verified).
//
// Design: full-width row streaming, global_load_lds DMA staging, producer/
// consumer wave split. R9/R11/R12 post-mortem: holding in-flight loads in
// VGPRs spills (allocator can't remat volatile-asm loads); the zero-VGPR
// mechanism for deep in-flight reads is global_load_lds (DMA -> LDS,
// counted by vmcnt).
//  - Block = 512-wide x SH=16-row strip. 22 image rows/block. Grid 32x16
//    = 512 blocks = 2/CU (LDS 65.8 KB).
//  - Raw ring: 4 slots x [6 ch-rows][512] staged 3 rows ahead by waves 0-1
//    (6 DMA instrs each, halves split by wave). 18 KB in flight per
//    producer wave, 72 KB/CU. Counted WAITV(18) steady-state, never 0.
//    Each producer wave reads only the half IT staged -> vmcnt suffices,
//    no barrier between DMA and consumption.
//  - Producers: channel-reduce raw -> t/u rows (x+4 offset, zero pads at
//    edges handle column zero-padding) in a 2-slot LDS ring.
//  - Consumers (waves 2-3): 4 cols/thread; 12 aligned ds_read_b128; static
//    window extraction; horizontal 7-tap slide; vertical 7-tap via
//    static-indexed 8-slot register ring; std + fused smooth-L1.
//  - ONE barrier per image row, at a wave-uniform point. Unroll period 8
//    keeps all ring/slot indices compile-time (no scratch).

typedef float f32x4 __attribute__((ext_vector_type(4)));

#define K      7
#define PAD    3
#define SH     16                // output rows per strip
#define NROW   (SH + K - 1)      // 22 staged rows
#define DD     3                 // stage-ahead depth
#define RS     4                 // raw ring slots
#define NT     256
#define IW     512
#define IH     512
#define TUW    520               // padded t/u row: 4 left + 512 + 4 right

#define WAITV(N) do {                                     \
    asm volatile("s_waitcnt vmcnt(" #N ")" ::: "memory"); \
    __builtin_amdgcn_sched_barrier(0);                    \
} while (0)

__device__ __forceinline__ void dma16(const float* g, float* l) {
    __builtin_amdgcn_global_load_lds(
        (const __attribute__((address_space(1))) void*)g,
        (__attribute__((address_space(3))) void*)l, 16, 0, 0);
}

__global__ __launch_bounds__(NT, 2) void dist_loss_kernel(
    const float* __restrict__ pred,
    const float* __restrict__ tgt,
    float* __restrict__ out)
{
    constexpr float INV_N     = 1.0f / 147.0f;
    constexpr float INV_TOTAL = 1.0f / (16.0f * 512.0f * 512.0f);

    extern __shared__ float smem[];
    float* raw_ = smem;                       // [RS][6][IW]
    float* tu_  = smem + RS * 6 * IW;         // [2 slot][2 in][2 kind][TUW]
    float* wsum = tu_ + 2 * 2 * 2 * TUW;      // [4]

    const int  tid  = threadIdx.x;
    const int  lane = tid & 63;
    const int  wv   = tid >> 6;               // 0..3
    const bool prod = (wv < 2);
    const int  ys   = blockIdx.x * SH;
    const int  b    = blockIdx.y;
    const size_t plane = (size_t)IH * IW;
    const float* base0 = pred + (size_t)b * 3 * plane;
    const float* base1 = tgt  + (size_t)b * 3 * plane;

    const int hw = wv;                 // producer half (valid for wv<2)
    const int cp = tid << 2;           // producer cols (tid 0..127 -> 0..508)
    const int cc = (tid - 128) << 2;   // consumer cols

    // t/u pad zero-init (rows are consecutive: 8 rows x TUW). Visibility to
    // first consumer read (iter 1) is ordered by iter 0's barrier.
    if (!prod) {
        int u = tid - 128;
        if (u < 64) {
            int row = u >> 3, p = u & 7;
            tu_[row * TUW + ((p < 4) ? p : (512 + p))] = 0.f;
        }
    }

    // consumer vertical ring (static-indexed); zero-init == zero row padding
    f32x4 ringh[2][8], ringg[2][8], S[2], Q[2];
    #pragma unroll
    for (int wi = 0; wi < 2; ++wi) {
        S[wi] = (f32x4){0.f, 0.f, 0.f, 0.f};
        Q[wi] = (f32x4){0.f, 0.f, 0.f, 0.f};
        #pragma unroll
        for (int r = 0; r < 8; ++r) {
            ringh[wi][r] = (f32x4){0.f, 0.f, 0.f, 0.f};
            ringg[wi][r] = (f32x4){0.f, 0.f, 0.f, 0.f};
        }
    }
    float acc = 0.f;

    // stage image row rr (clamped) into raw slot: 6 DMA, this wave's half
    #define STAGE(rr, slot) do {                                             \
        const int gy_  = ys - PAD + (rr);                                    \
        const int gyc_ = min(max(gy_, 0), IH - 1);                           \
        const float* g0_ = base0 + (size_t)gyc_ * IW + (hw << 8) + (lane << 2); \
        const float* g1_ = base1 + (size_t)gyc_ * IW + (hw << 8) + (lane << 2); \
        float* lb_ = raw_ + (slot) * 6 * IW + (hw << 8);                     \
        dma16(g0_,              lb_);                                        \
        dma16(g0_ + plane,      lb_ + IW);                                   \
        dma16(g0_ + 2 * plane,  lb_ + 2 * IW);                               \
        dma16(g1_,              lb_ + 3 * IW);                               \
        dma16(g1_ + plane,      lb_ + 4 * IW);                               \
        dma16(g1_ + 2 * plane,  lb_ + 5 * IW);                               \
    } while (0)

    // channel reduce row i_ from raw slot SLT -> t/u ring slot TSL
    #define TUC(i_, SLT, TSL) do {                                           \
        const int   gy_ = ys - PAD + (i_);                                   \
        const float m_  = ((unsigned)gy_ < (unsigned)IH) ? 1.f : 0.f;        \
        const float* rb_ = raw_ + (SLT) * 6 * IW + cp;                       \
        f32x4 q0 = *(const f32x4*)(rb_);                                     \
        f32x4 q1 = *(const f32x4*)(rb_ + IW);                                \
        f32x4 q2 = *(const f32x4*)(rb_ + 2 * IW);                            \
        f32x4 q3 = *(const f32x4*)(rb_ + 3 * IW);                            \
        f32x4 q4 = *(const f32x4*)(rb_ + 4 * IW);                            \
        f32x4 q5 = *(const f32x4*)(rb_ + 5 * IW);                            \
        f32x4 t0 = (q0 + q1 + q2) * m_;                                      \
        f32x4 u0 = (q0 * q0 + q1 * q1 + q2 * q2) * m_;                       \
        f32x4 t1 = (q3 + q4 + q5) * m_;                                      \
        f32x4 u1 = (q3 * q3 + q4 * q4 + q5 * q5) * m_;                       \
        float* tb_ = tu_ + (TSL) * (4 * TUW) + cp + 4;                       \
        *(f32x4*)(tb_)           = t0;                                       \
        *(f32x4*)(tb_ + TUW)     = u0;                                       \
        *(f32x4*)(tb_ + 2 * TUW) = t1;                                       \
        *(f32x4*)(tb_ + 3 * TUW) = u1;                                       \
    } while (0)

    // one horizontal slide: 3 aligned b128 at row base RB_ -> hv (4 cols)
    #define HSLIDE(RB_, HV_) do {                                            \
        f32x4 a_ = *(const f32x4*)(RB_);                                     \
        f32x4 b_ = *(const f32x4*)((RB_) + 4);                               \
        f32x4 c_ = *(const f32x4*)((RB_) + 8);                               \
        float h0 = a_[1] + a_[2] + a_[3] + b_[0] + b_[1] + b_[2] + b_[3];    \
        float h1 = h0 - a_[1] + c_[0];                                       \
        float h2 = h1 - a_[2] + c_[1];                                       \
        float h3 = h2 - a_[3] + c_[2];                                       \
        HV_ = (f32x4){h0, h1, h2, h3};                                       \
    } while (0)

    // consumer: row r = i_-1 from t/u slot TSL; ring new=JN old=JO (static)
    #define CONS(i_, TSL, JN, JO) do {                                       \
        const float* tb_ = tu_ + (TSL) * (4 * TUW) + cc;                     \
        f32x4 hv_;                                                           \
        HSLIDE(tb_, hv_);                                                    \
        S[0] += hv_ - ringh[0][JO]; ringh[0][JN] = hv_;                      \
        HSLIDE(tb_ + TUW, hv_);                                              \
        Q[0] += hv_ - ringg[0][JO]; ringg[0][JN] = hv_;                      \
        HSLIDE(tb_ + 2 * TUW, hv_);                                          \
        S[1] += hv_ - ringh[1][JO]; ringh[1][JN] = hv_;                      \
        HSLIDE(tb_ + 3 * TUW, hv_);                                          \
        Q[1] += hv_ - ringg[1][JO]; ringg[1][JN] = hv_;                      \
        if ((i_) >= 7) {                                                     \
            _Pragma("unroll")                                                \
            for (int e_ = 0; e_ < 4; ++e_) {                                 \
                float mu0 = S[0][e_] * INV_N;                                \
                float s0_ = sqrtf(fmaf(-mu0, mu0, Q[0][e_] * INV_N) + 1e-8f);\
                float mu1 = S[1][e_] * INV_N;                                \
                float s1_ = sqrtf(fmaf(-mu1, mu1, Q[1][e_] * INV_N) + 1e-8f);\
                float d_  = s0_ - s1_;                                       \
                float ad_ = fabsf(d_);                                       \
                acc += (ad_ < 1.f) ? 0.5f * d_ * d_ : (ad_ - 0.5f);          \
            }                                                                \
        }                                                                    \
    } while (0)

    // one barrel iteration; j_ = i_ & 7 must be compile-time static
    #define ITER(i_, j_, NW_) do {                                           \
        if (prod) {                                                          \
            if ((i_) + DD < NROW) STAGE((i_) + DD, ((j_) + DD) & 3);         \
            WAITV(NW_);                                                      \
            if ((i_) < NROW) TUC((i_), (j_) & 3, (j_) & 1);                  \
        } else {                                                             \
            if ((i_) >= 1) CONS((i_), ((j_) + 1) & 1, ((j_) + 7) & 7, (j_)); \
        }                                                                    \
        __syncthreads();                                                     \
    } while (0)

    // prologue: rows 0..2 in flight (18 loads/producer wave)
    if (prod) { STAGE(0, 0); STAGE(1, 1); STAGE(2, 2); }

    // main: iters 0..15 (stage always legal, steady-state WAITV(18))
    #pragma unroll 1
    for (int g = 0; g < 2; ++g) {
        #pragma unroll
        for (int j = 0; j < 8; ++j) {
            ITER(g * 8 + j, j, 18);
        }
    }
    // tail: iters 16..22 explicit (drain 18/18/18/12/6/0/0)
    ITER(16, 0, 18);
    ITER(17, 1, 18);
    ITER(18, 2, 18);
    ITER(19, 3, 12);
    ITER(20, 4, 6);
    ITER(21, 5, 0);
    ITER(22, 6, 0);

    #undef ITER
    #undef CONS
    #undef HSLIDE
    #undef TUC
    #undef STAGE

    // reduction: wave shuffle, cross-wave via LDS, one atomic per block
    #pragma unroll
    for (int off = 32; off > 0; off >>= 1)
        acc += __shfl_down(acc, off, 64);
    if (lane == 0) wsum[wv] = acc;
    __syncthreads();
    if (tid == 0) {
        float s = wsum[0] + wsum[1] + wsum[2] + wsum[3];
        atomicAdd(out, s * INV_TOTAL);
    }
}

extern "C" void kernel_launch(void* const* d_in, const int* in_sizes, int n_in,
                              void* d_out, int out_size, void* d_ws, size_t ws_size,
                              hipStream_t stream) {
    const float* pred = (const float*)d_in[0];
    const float* tgt  = (const float*)d_in[1];
    float* out = (float*)d_out;

    hipMemsetAsync(out, 0, sizeof(float), stream);

    const size_t lds_bytes = (RS * 6 * IW + 2 * 2 * 2 * TUW + 4) * sizeof(float);

    dim3 grid(IH / SH, 16);   // 32 strips x 16 batches = 512 blocks, 2/CU
    dist_loss_kernel<<<grid, NT, lds_bytes, stream>>>(pred, tgt, out);
}